// Round 2
// 1060.442 us; speedup vs baseline: 1.0214x; 1.0214x over previous
//
#include <hip/hip_runtime.h>
#include <hip/hip_bf16.h>

typedef __hip_bfloat16 bf16;
typedef __attribute__((ext_vector_type(8))) short bf16x8;
typedef __attribute__((ext_vector_type(4))) float f32x4;

#define N_NODES 50000
#define N_EDGES 800000
#define DIM 128
#define QKVW 384

__device__ __forceinline__ void storeO(float* p, float v){ *p = v; }
__device__ __forceinline__ void storeO(bf16* p, float v){ *p = __float2bfloat16(v); }
__device__ __forceinline__ float bfu2f(unsigned short u){
  return __uint_as_float(((unsigned)u) << 16);
}
__device__ __forceinline__ unsigned short f2bfbits(float f){
  bf16 t = __float2bfloat16(f);
  return *reinterpret_cast<unsigned short*>(&t);
}

__global__ void fill_kernel(unsigned* __restrict__ p, unsigned val, int n){
  int i = blockIdx.x * blockDim.x + threadIdx.x;
  if (i < n) p[i] = val;
}

// batched transpose+bf16: W[l][K][M] fp32 -> Wt[l][M][K] bf16
__global__ void prep_w_kernel(const float* __restrict__ W, bf16* __restrict__ Wt,
    int K, int M, int L){
  int idx = blockIdx.x * blockDim.x + threadIdx.x;
  int tot = L * K * M;
  if (idx >= tot) return;
  int l = idx / (K * M), r = idx - l * (K * M);
  int m = r / K, k = r - m * K;
  Wt[idx] = __float2bfloat16(W[(size_t)l * K * M + (size_t)k * M + m]);
}

// qkv packed layout is [q | v | k] so attn can read q and v with one base
// pointer (v at constant +256B). k sits at +512B, read once per dst.
__global__ void prep_qkvw_kernel(const float* __restrict__ Wq, const float* __restrict__ Wk,
    const float* __restrict__ Wv, bf16* __restrict__ Wt){
  int idx = blockIdx.x * blockDim.x + threadIdx.x;
  if (idx >= 5 * QKVW * 128) return;
  int l = idx / (QKVW * 128), r = idx - l * (QKVW * 128);
  int m = r / 128, k = r - m * 128;
  const float* src = (m < 128) ? (Wq + (size_t)l * 16384 + (size_t)k * 128 + m)
                   : (m < 256) ? (Wv + (size_t)l * 16384 + (size_t)k * 128 + (m - 128))
                               : (Wk + (size_t)l * 16384 + (size_t)k * 128 + (m - 256));
  Wt[idx] = __float2bfloat16(*src);
}

__global__ void pack_qkvbias_kernel(const float* __restrict__ bq, const float* __restrict__ bk,
    const float* __restrict__ bv, float* __restrict__ bqkv){
  int i = blockIdx.x * blockDim.x + threadIdx.x;
  if (i >= 5 * QKVW) return;
  int l = i / QKVW, j = i - l * QKVW;
  float v = (j < 128) ? bq[l * 128 + j] : (j < 256) ? bv[l * 128 + j - 128] : bk[l * 128 + j - 256];
  bqkv[i] = v;
}

// ---- CSR build: hist -> 3-phase parallel scan -> scatter ----
__global__ void hist_kernel(const int* __restrict__ dst, int* __restrict__ counts, int E){
  int e = blockIdx.x * blockDim.x + threadIdx.x;
  if (e < E) atomicAdd(counts + dst[e], 1);
}

__global__ __launch_bounds__(256) void blockscan_kernel(const int* __restrict__ counts,
    int* __restrict__ rowptr, int* __restrict__ bsum, int n){
  __shared__ int buf[256];
  int t = threadIdx.x, i = blockIdx.x * 256 + t;
  int x = (i < n) ? counts[i] : 0;
  buf[t] = x; __syncthreads();
  #pragma unroll
  for (int off = 1; off < 256; off <<= 1){
    int v = (t >= off) ? buf[t - off] : 0;
    __syncthreads(); buf[t] += v; __syncthreads();
  }
  if (i < n) rowptr[i] = buf[t] - x;
  if (t == 255) bsum[blockIdx.x] = buf[255];
}

__global__ __launch_bounds__(256) void scanb_kernel(int* __restrict__ bsum, int nb){
  __shared__ int buf[256];
  int t = threadIdx.x;
  int x = (t < nb) ? bsum[t] : 0;
  buf[t] = x; __syncthreads();
  #pragma unroll
  for (int off = 1; off < 256; off <<= 1){
    int v = (t >= off) ? buf[t - off] : 0;
    __syncthreads(); buf[t] += v; __syncthreads();
  }
  if (t < nb) bsum[t] = buf[t] - x;
  if (t == nb - 1) bsum[nb] = buf[t];
}

__global__ void addoff_kernel(int* __restrict__ rowptr, const int* __restrict__ bsum,
    int n, int nb){
  int i = blockIdx.x * blockDim.x + threadIdx.x;
  if (i < n) rowptr[i] += bsum[i >> 8];
  if (i == 0) rowptr[n] = bsum[nb];
}

__global__ void scatter_kernel(const int* __restrict__ src, const int* __restrict__ dst,
    const int* __restrict__ rowptr, int* __restrict__ cursor,
    int* __restrict__ srclist, int E){
  int e = blockIdx.x * blockDim.x + threadIdx.x;
  if (e >= E) return;
  int d = dst[e];
  int pos = rowptr[d] + atomicAdd(cursor + d, 1);
  srclist[pos] = src[e];
}

// ---- gather attention v2: lane = (edge-slot 0..3) x (feature-slot 0..15).
// Each lane owns 8 contiguous elems (16B dwordx4) of one edge's q/v row and
// head t>>1. One q-load + one v-load instruction covers 4 edges (1KB each).
// Score reduce = single shfl_xor(p,1); exp once per 4 edges per lane-pair;
// cross-edge reduce deferred to one 2-level butterfly at wave end.
// NO-MAX softmax (scores provably < ~20; ratio shift-invariant); k prescaled
// by 1/sqrt(16). qkv layout [q|v|k].
__global__ __launch_bounds__(256) void attn_kernel(
    const int* __restrict__ rowptr, const int* __restrict__ srclist,
    const bf16* __restrict__ qkv, bf16* __restrict__ agg, int n){
  int d = blockIdx.x * 4 + (threadIdx.x >> 6);
  int lane = threadIdx.x & 63;
  if (d >= n) return;
  int eslot = lane >> 4;          // 0..3 edge slot
  int t = lane & 15;              // feature slot: elems 8t..8t+7, head = t>>1
  // k slice for this lane, prescaled
  float kf[8];
  {
    const int4* kp = (const int4*)(qkv + (size_t)d * QKVW + 256 + t * 8);
    int4 kv = kp[0];
    const unsigned* ku = (const unsigned*)&kv;
    #pragma unroll
    for (int j = 0; j < 4; j++){
      kf[2*j]   = __uint_as_float(ku[j] << 16) * 0.25f;
      kf[2*j+1] = __uint_as_float(ku[j] & 0xffff0000u) * 0.25f;
    }
  }
  float acc[8];
  #pragma unroll
  for (int j = 0; j < 8; j++) acc[j] = 0.f;
  float den = 0.f;
  int e = rowptr[d], e1 = rowptr[d + 1];
  for (; e < e1; e += 8){
    int eeA = e + eslot, eeB = e + 4 + eslot;
    int sA = srclist[(eeA < e1) ? eeA : (e1 - 1)];
    int sB = srclist[(eeB < e1) ? eeB : (e1 - 1)];
    const int4* qpA = (const int4*)(qkv + (size_t)sA * QKVW + t * 8);
    const int4* qpB = (const int4*)(qkv + (size_t)sB * QKVW + t * 8);
    int4 qA = qpA[0];
    int4 vA = qpA[16];            // +256B = v slice
    int4 qB = qpB[0];
    int4 vB = qpB[16];
    float pA = 0.f, pB = 0.f;
    const unsigned* qa = (const unsigned*)&qA;
    const unsigned* qb = (const unsigned*)&qB;
    #pragma unroll
    for (int j = 0; j < 4; j++){
      pA = fmaf(__uint_as_float(qa[j] << 16),          kf[2*j],   pA);
      pA = fmaf(__uint_as_float(qa[j] & 0xffff0000u),  kf[2*j+1], pA);
      pB = fmaf(__uint_as_float(qb[j] << 16),          kf[2*j],   pB);
      pB = fmaf(__uint_as_float(qb[j] & 0xffff0000u),  kf[2*j+1], pB);
    }
    pA += __shfl_xor(pA, 1);      // head-pair reduce (head spans 2 lanes)
    pB += __shfl_xor(pB, 1);
    float wA = (eeA < e1) ? __expf(pA) : 0.f;
    float wB = (eeB < e1) ? __expf(pB) : 0.f;
    den += wA + wB;               // per-head denom (lane's head)
    const unsigned* va = (const unsigned*)&vA;
    const unsigned* vb = (const unsigned*)&vB;
    #pragma unroll
    for (int j = 0; j < 4; j++){
      acc[2*j]   = fmaf(wA, __uint_as_float(va[j] << 16),         acc[2*j]);
      acc[2*j+1] = fmaf(wA, __uint_as_float(va[j] & 0xffff0000u), acc[2*j+1]);
      acc[2*j]   = fmaf(wB, __uint_as_float(vb[j] << 16),         acc[2*j]);
      acc[2*j+1] = fmaf(wB, __uint_as_float(vb[j] & 0xffff0000u), acc[2*j+1]);
    }
  }
  // reduce over the 4 edge slots (lane bits 4,5)
  #pragma unroll
  for (int m = 16; m <= 32; m <<= 1){
    den += __shfl_xor(den, m);
    #pragma unroll
    for (int j = 0; j < 8; j++) acc[j] += __shfl_xor(acc[j], m);
  }
  if (eslot == 0){
    float inv = (den > 0.f) ? 1.f / den : 0.f;
    unsigned short o[8];
    #pragma unroll
    for (int j = 0; j < 8; j++) o[j] = f2bfbits(acc[j] * inv);
    *(int4*)(agg + (size_t)d * DIM + t * 8) = *(const int4*)o;
  }
}

// ---- MFMA GEMM v4: A staged once in small LDS; W fragments ping-pong
// double-buffered per col-tile (single-use -> prefetch, not resident).
// VGPR capped for 4 waves/EU on KT=128. One barrier total.
template<int KT, int MT, typename AT, bool FUSELN, bool RELU, bool RESID, typename OT>
__global__ __launch_bounds__(256, (KT == 128) ? 4 : 2) void pgemm4(
    const AT* __restrict__ A, const float* __restrict__ lng, const float* __restrict__ lnb,
    const bf16* __restrict__ Wt, const float* __restrict__ bias,
    const float* __restrict__ resid, OT* __restrict__ out, float* __restrict__ out2,
    int n, int M){
  constexpr int CPR = KT / 8;              // 16B chunks per A row
  constexpr int CPT = (64 * CPR) / 256;    // chunks per thread
  constexpr int NMT = MT / 64;             // col-tiles
  constexpr int NKS = KT / 32;             // k-steps
  __shared__ short Ash[64][KT + 8];
  int tid = threadIdx.x;
  int wv = tid >> 6, lane = tid & 63;
  int l15 = lane & 15, quad = lane >> 4;
  int bm = blockIdx.x * 64;

  bf16x8 wf[2][NKS];
  auto loadW = [&](int mt, int b){
    int col = mt * 64 + wv * 16 + l15;
    #pragma unroll
    for (int ks = 0; ks < NKS; ks++){
      int4 w = make_int4(0, 0, 0, 0);
      if (col < M) w = *(const int4*)(Wt + (size_t)col * KT + ks * 32 + quad * 8);
      wf[b][ks] = *(bf16x8*)&w;
    }
  };
  loadW(0, 0);   // prefetch first col-tile during A staging

  // stage A row-block (convert fp32->bf16, optional fused LN)
  #pragma unroll
  for (int i = 0; i < CPT; i++){
    int c = tid + i * 256;
    int row = c / CPR, off = (c - row * CPR) * 8;
    int gr = bm + row;
    if constexpr (sizeof(AT) == 4){
      float va[8];
      if (gr < n){
        float4 f0 = *(const float4*)(A + (size_t)gr * KT + off);
        float4 f1 = *(const float4*)(A + (size_t)gr * KT + off + 4);
        va[0]=f0.x; va[1]=f0.y; va[2]=f0.z; va[3]=f0.w;
        va[4]=f1.x; va[5]=f1.y; va[6]=f1.z; va[7]=f1.w;
      } else {
        #pragma unroll
        for (int j = 0; j < 8; j++) va[j] = 0.f;
      }
      if constexpr (FUSELN){  // KT==128: 16 consecutive lanes own one row
        float s = va[0]+va[1]+va[2]+va[3]+va[4]+va[5]+va[6]+va[7];
        s += __shfl_xor(s, 1); s += __shfl_xor(s, 2);
        s += __shfl_xor(s, 4); s += __shfl_xor(s, 8);
        float mu = s * (1.f / 128.f);
        float vs = 0.f;
        #pragma unroll
        for (int j = 0; j < 8; j++){ float dd = va[j] - mu; vs += dd * dd; }
        vs += __shfl_xor(vs, 1); vs += __shfl_xor(vs, 2);
        vs += __shfl_xor(vs, 4); vs += __shfl_xor(vs, 8);
        float rs = rsqrtf(vs * (1.f / 128.f) + 1e-5f);
        float4 g0 = *(const float4*)(lng + off);
        float4 g1 = *(const float4*)(lng + off + 4);
        float4 b0 = *(const float4*)(lnb + off);
        float4 b1 = *(const float4*)(lnb + off + 4);
        va[0]=(va[0]-mu)*rs*g0.x+b0.x; va[1]=(va[1]-mu)*rs*g0.y+b0.y;
        va[2]=(va[2]-mu)*rs*g0.z+b0.z; va[3]=(va[3]-mu)*rs*g0.w+b0.w;
        va[4]=(va[4]-mu)*rs*g1.x+b1.x; va[5]=(va[5]-mu)*rs*g1.y+b1.y;
        va[6]=(va[6]-mu)*rs*g1.z+b1.z; va[7]=(va[7]-mu)*rs*g1.w+b1.w;
      }
      unsigned short tmp[8];
      #pragma unroll
      for (int j = 0; j < 8; j++) tmp[j] = f2bfbits(va[j]);
      *(int4*)(&Ash[row][off]) = *(const int4*)tmp;
    } else {
      int4 av = make_int4(0, 0, 0, 0);
      if (gr < n) av = *(const int4*)(A + (size_t)gr * KT + off);
      *(int4*)(&Ash[row][off]) = av;
    }
  }
  __syncthreads();

  #pragma unroll
  for (int mt = 0; mt < NMT; mt++){
    int b = mt & 1;
    if (mt + 1 < NMT) loadW(mt + 1, b ^ 1);   // prefetch next tile's W
    f32x4 acc[4];
    #pragma unroll
    for (int i = 0; i < 4; i++) acc[i] = (f32x4){0.f, 0.f, 0.f, 0.f};
    #pragma unroll
    for (int ks = 0; ks < NKS; ks++){
      bf16x8 bfrag = wf[b][ks];
      #pragma unroll
      for (int mi = 0; mi < 4; mi++){
        bf16x8 afrag = *(const bf16x8*)(&Ash[mi * 16 + l15][ks * 32 + quad * 8]);
        acc[mi] = __builtin_amdgcn_mfma_f32_16x16x32_bf16(afrag, bfrag, acc[mi], 0, 0, 0);
      }
    }
    int col = mt * 64 + wv * 16 + l15;
    if (col < M){
      float bval = bias[col];
      #pragma unroll
      for (int mi = 0; mi < 4; mi++){
        int row0 = bm + mi * 16 + quad * 4;
        #pragma unroll
        for (int rg = 0; rg < 4; rg++){
          int grow = row0 + rg;
          if (grow >= n) continue;
          float v = acc[mi][rg] + bval;
          if (RELU) v = fmaxf(v, 0.f);
          if (RESID) v += resid[(size_t)grow * M + col];
          storeO(out + (size_t)grow * M + col, v);
          if (out2) out2[(size_t)grow * M + col] = v;
        }
      }
    }
  }
}

extern "C" void kernel_launch(void* const* d_in, const int* in_sizes, int n_in,
                              void* d_out, int out_size, void* d_ws, size_t ws_size,
                              hipStream_t stream) {
  const float* x    = (const float*)d_in[0];
  const int*  esrc  = (const int*)d_in[1];
  const int*  edst  = (const int*)d_in[2];
  const float* Wi   = (const float*)d_in[3];
  const float* bi   = (const float*)d_in[4];
  const float* Wq   = (const float*)d_in[5];
  const float* bq   = (const float*)d_in[6];
  const float* Wk   = (const float*)d_in[7];
  const float* bk   = (const float*)d_in[8];
  const float* Wv   = (const float*)d_in[9];
  const float* bv   = (const float*)d_in[10];
  const float* Wo   = (const float*)d_in[11];
  const float* bo   = (const float*)d_in[12];
  const float* g1   = (const float*)d_in[13];
  const float* b1   = (const float*)d_in[14];
  const float* Wf1  = (const float*)d_in[15];
  const float* bf1  = (const float*)d_in[16];
  const float* Wf2  = (const float*)d_in[17];
  const float* bf2  = (const float*)d_in[18];
  const float* gout = (const float*)d_in[19];
  const float* bout_ln = (const float*)d_in[20];
  const float* Wout = (const float*)d_in[21];
  const float* bout = (const float*)d_in[22];

  const size_t ND = (size_t)N_NODES * DIM;   // 6.4M
  float* ws = (float*)d_ws;
  float* h   = ws;                            // ND f32
  bf16* agg  = (bf16*)(ws + ND);              // ND bf16
  bf16* qkv  = (bf16*)(ws + ND + ND / 2);     // N*384 bf16
  bf16* mid  = qkv;                           // overlay [N,256] bf16
  float* after_qkv = ws + ND + ND / 2 + ((size_t)N_NODES * QKVW) / 2;
  bf16* Wit    = (bf16*)after_qkv;                   // 128*256
  bf16* Wqkvt  = Wit + 128 * 256;                    // 5*384*128
  bf16* Wot    = Wqkvt + 5 * QKVW * 128;             // 5*128*128
  bf16* Wf1t   = Wot + 5 * 128 * 128;                // 5*256*128
  bf16* Wf2t   = Wf1t + 5 * 256 * 128;               // 5*128*256
  bf16* Woutt  = Wf2t + 5 * 128 * 256;               // 40*128
  float* bqkv  = (float*)(Woutt + 40 * 128);         // 5*384 f32
  int* rowptr  = (int*)(bqkv + 5 * QKVW);            // N+1
  int* cnt     = rowptr + N_NODES + 1;               // N
  int* bsum    = cnt + N_NODES;                      // 197
  int* srclist = bsum + 200;                         // E

  dim3 B(256);
  const int EB = (N_EDGES + 255) / 256;
  const int NB = (N_NODES + 255) / 256;
  const int NSB = (N_NODES + 255) / 256;             // 196 scan blocks
  dim3 Grow(782);

  // ---- prep ----
  prep_w_kernel<<<(1 * 256 * 128 + 255) / 256, B, 0, stream>>>(Wi, Wit, 256, 128, 1);
  prep_qkvw_kernel<<<(5 * QKVW * 128 + 255) / 256, B, 0, stream>>>(Wq, Wk, Wv, Wqkvt);
  prep_w_kernel<<<(5 * 128 * 128 + 255) / 256, B, 0, stream>>>(Wo, Wot, 128, 128, 5);
  prep_w_kernel<<<(5 * 128 * 256 + 255) / 256, B, 0, stream>>>(Wf1, Wf1t, 128, 256, 5);
  prep_w_kernel<<<(5 * 256 * 128 + 255) / 256, B, 0, stream>>>(Wf2, Wf2t, 256, 128, 5);
  prep_w_kernel<<<(1 * 128 * 40 + 255) / 256, B, 0, stream>>>(Wout, Woutt, 128, 40, 1);
  pack_qkvbias_kernel<<<(5 * QKVW + 255) / 256, B, 0, stream>>>(bq, bk, bv, bqkv);
  fill_kernel<<<NB, B, 0, stream>>>((unsigned*)cnt, 0u, N_NODES);
  hist_kernel<<<EB, B, 0, stream>>>(edst, cnt, N_EDGES);
  blockscan_kernel<<<NSB, B, 0, stream>>>(cnt, rowptr, bsum, N_NODES);
  scanb_kernel<<<1, B, 0, stream>>>(bsum, NSB);
  addoff_kernel<<<NB, B, 0, stream>>>(rowptr, bsum, N_NODES, NSB);
  fill_kernel<<<NB, B, 0, stream>>>((unsigned*)cnt, 0u, N_NODES);
  scatter_kernel<<<EB, B, 0, stream>>>(esrc, edst, rowptr, cnt, srclist, N_EDGES);

  // h = relu(x @ Wi + bi)
  pgemm4<256, 128, float, false, true, false, float><<<Grow, B, 0, stream>>>(
      x, nullptr, nullptr, Wit, bi, nullptr, h, nullptr, N_NODES, 128);

  for (int l = 0; l < 5; l++){
    // qkv = LN(h) @ [Wq|Wv|Wk] + bias  (LN fused)
    pgemm4<128, 384, float, true, false, false, bf16><<<Grow, B, 0, stream>>>(
        h, g1 + l * DIM, b1 + l * DIM, Wqkvt + (size_t)l * QKVW * 128,
        bqkv + l * QKVW, nullptr, qkv, nullptr, N_NODES, QKVW);
    attn_kernel<<<12500, B, 0, stream>>>(rowptr, srclist, qkv, agg, N_NODES);
    // h = h + agg @ Wo + bo
    pgemm4<128, 128, bf16, false, false, true, float><<<Grow, B, 0, stream>>>(
        agg, nullptr, nullptr, Wot + (size_t)l * 128 * 128, bo + l * DIM,
        h, h, nullptr, N_NODES, 128);
    // mid = relu(LN(h) @ Wf1 + bf1)  (reference reuses g1/b1)
    pgemm4<128, 256, float, true, true, false, bf16><<<Grow, B, 0, stream>>>(
        h, g1 + l * DIM, b1 + l * DIM, Wf1t + (size_t)l * 256 * 128,
        bf1 + l * 2 * DIM, nullptr, mid, nullptr, N_NODES, 256);
    // h = h + mid @ Wf2 + bf2 ; last layer dual-writes d_out (mid output)
    float* out2 = (l == 4) ? (float*)d_out : nullptr;
    pgemm4<256, 128, bf16, false, false, true, float><<<Grow, B, 0, stream>>>(
        mid, nullptr, nullptr, Wf2t + (size_t)l * 128 * 256, bf2 + l * DIM,
        h, h, out2, N_NODES, 128);
  }

  // out = LN(h, g_out, b_out) @ Wout + bout  (M=40)
  pgemm4<128, 64, float, true, false, false, float><<<Grow, B, 0, stream>>>(
      h, gout, bout_ln, Woutt, bout, nullptr, ((float*)d_out) + ND, nullptr, N_NODES, 40);
}